// Round 9
// baseline (1535.038 us; speedup 1.0000x reference)
//
#include <hip/hip_runtime.h>
#include <hip/hip_fp16.h>
#include <math.h>

// ---------------------------------------------------------------------------
// ArcHybridLSTM forward on MI355X — round 9: launchable spill-free LSTM.
//   1. embed_h:      ivec_h[B*S,192] fp16 (160 real + 32 zero-pad)
//   2. mfma_gemm<.,1>: xgs = swizzled(ivec_h @ Wih^T + bias)  [B*S][c*4+gate] f32
//   3. lstm_rec L1:  -> vec1h[B*S,512] fp16
//   4. mfma_gemm<.,1>: xgs2 (K=512)
//   5. lstm_rec L2:  -> vec2h fp16
//   6. mfma_gemm_g256: hidc_h = tanh(feats@[hid|rhid]^T+b), K=6144, 256x128 tile
//   7. mfma_gemm<false,3>: heads via W96 (K=1024) -> d_out
//
// ROUND-8 FINDING: __launch_bounds__(512,N) 2nd arg lowers CUDA-style
// (min blocks/CU): N=2 -> 4 waves/EU -> 128-VGPR cap -> weights spilled to
// scratch (rounds 3-7: VGPR_Count=128, +57MB WRITE_SIZE). N=1 lets the
// allocator exceed 256 VGPRs, but an 8-wave WG needs 2 waves/SIMD ->
// unlaunchable -> round-8 abort. Fix: amdgpu_waves_per_eu(2) pins the cap
// at exactly 512/2 = 256 VGPRs — spill-free AND launchable.
// lstm v8: 48 pairs/gate VGPR (192 regs) + 16 pairs/gate swizzled LDS (128KB).
// ---------------------------------------------------------------------------

namespace {
constexpr int kB = 64, kS = 256, kH = 256, kG4 = 1024;   // batch, seq, hidden, 4H
constexpr int kLD = 512;                                 // LSTM concat dim
constexpr int kTok = kB * kS;                            // 16384 rows everywhere
}

typedef _Float16 h2 __attribute__((ext_vector_type(2)));
typedef _Float16 h4 __attribute__((ext_vector_type(4)));
typedef _Float16 h8 __attribute__((ext_vector_type(8)));
typedef float f4 __attribute__((ext_vector_type(4)));

#if __has_builtin(__builtin_amdgcn_fdot2)
#define USE_FDOT2 1
#else
#define USE_FDOT2 0
#endif

__device__ __forceinline__ float dot2acc(h2 w, h2 hh, float acc) {
#if USE_FDOT2
  return __builtin_amdgcn_fdot2(w, hh, acc, false);
#else
  return fmaf((float)w.x, (float)hh.x, fmaf((float)w.y, (float)hh.y, acc));
#endif
}

__device__ __forceinline__ float fastrcp(float x) {
#if __has_builtin(__builtin_amdgcn_rcpf)
  return __builtin_amdgcn_rcpf(x);
#else
  return 1.f / x;
#endif
}
__device__ __forceinline__ float sigf(float x) { return fastrcp(1.f + __expf(-x)); }
__device__ __forceinline__ float tanhfast(float x) {
  float u = __expf(2.f * x);
  return 1.f - 2.f * fastrcp(u + 1.f);
}

// pair-combine: x + (x from lane^1), VALU-pipe via DPP quad_perm [1,0,3,2]
__device__ __forceinline__ float dppadd1(float x) {
#if __has_builtin(__builtin_amdgcn_mov_dpp)
  int y = __builtin_amdgcn_mov_dpp(__builtin_bit_cast(int, x), 0xB1, 0xF, 0xF, true);
  return x + __builtin_bit_cast(float, y);
#else
  return x + __shfl_xor(x, 1);
#endif
}

// 16B global->LDS stage. lds_base must be wave-uniform; lane writes base+l*16.
__device__ __forceinline__ void stage16(const void* g, void* lds_base, int lane) {
#if __has_builtin(__builtin_amdgcn_global_load_lds)
  (void)lane;
  __builtin_amdgcn_global_load_lds((const __attribute__((address_space(1))) void*)g,
                                   (__attribute__((address_space(3))) void*)lds_base,
                                   16, 0, 0);
#else
  *(uint4*)((char*)lds_base + lane * 16) = *(const uint4*)g;
#endif
}

// ---------------- embeddings -> fp16, K padded 160->192 ----------------
__global__ void embed_h(const int* __restrict__ wid, const int* __restrict__ pid,
                        const float* __restrict__ wl, const float* __restrict__ pl,
                        _Float16* __restrict__ dst) {
  int tid = blockIdx.x * blockDim.x + threadIdx.x;  // kTok * 24 chunks of 8 cols
  if (tid >= kTok * 24) return;
  int tok = tid / 24, c8 = tid % 24;
  h8 o;
  if (c8 < 20) {
    const float* src = (c8 < 16) ? (wl + (size_t)wid[tok] * 128 + c8 * 8)
                                 : (pl + (size_t)pid[tok] * 32 + (c8 - 16) * 8);
    float4 v0 = *(const float4*)src;
    float4 v1 = *(const float4*)(src + 4);
    o[0] = (_Float16)v0.x; o[1] = (_Float16)v0.y;
    o[2] = (_Float16)v0.z; o[3] = (_Float16)v0.w;
    o[4] = (_Float16)v1.x; o[5] = (_Float16)v1.y;
    o[6] = (_Float16)v1.z; o[7] = (_Float16)v1.w;
  } else {
    o = (h8)(_Float16)0.f;
  }
  *(h8*)(dst + (size_t)tok * 192 + c8 * 8) = o;
}

// ---------------- fp32 -> fp16 with K zero-pad ----------------
__global__ void f2h_pad(const float* __restrict__ src, _Float16* __restrict__ dst,
                        int rows, int Kin, int Kpad) {
  int per = Kpad >> 2;
  int tid = blockIdx.x * blockDim.x + threadIdx.x;
  if (tid >= rows * per) return;
  int row = tid / per, c4 = (tid % per) << 2;
  h4 o;
  if (c4 < Kin) {
    float4 v = *(const float4*)(src + (size_t)row * Kin + c4);
    o[0] = (_Float16)v.x; o[1] = (_Float16)v.y;
    o[2] = (_Float16)v.z; o[3] = (_Float16)v.w;
  } else {
    o = (h4)(_Float16)0.f;
  }
  *(h4*)(dst + (size_t)row * Kpad + c4) = o;
}

// ---------------- bias sums (bih+bhh per layer/dir) ----------------
__global__ void prep_bias(const float* __restrict__ b0, const float* __restrict__ b1,
                          const float* __restrict__ b2, const float* __restrict__ b3,
                          const float* __restrict__ b4, const float* __restrict__ b5,
                          const float* __restrict__ b6, const float* __restrict__ b7,
                          float* __restrict__ bsum) {
  int tid = blockIdx.x * blockDim.x + threadIdx.x;
  if (tid >= 4 * kG4) return;
  int grp = tid >> 10, i = tid & 1023;
  const float* x; const float* y;
  switch (grp) {
    case 0: x = b0; y = b1; break;
    case 1: x = b2; y = b3; break;
    case 2: x = b4; y = b5; break;
    default: x = b6; y = b7; break;
  }
  bsum[tid] = x[i] + y[i];
}

__global__ void concat_bias(const float* __restrict__ a, const float* __restrict__ b,
                            float* __restrict__ dst) {
  int tid = blockIdx.x * blockDim.x + threadIdx.x;
  if (tid >= kG4) return;
  dst[tid] = (tid < 512) ? a[tid] : b[tid - 512];
}

// ---------------- heads weight: W96[128][1024] = [outL|0 ; 0|routL] --------
__global__ void build_w96(const float* __restrict__ outL, const float* __restrict__ outB,
                          const float* __restrict__ routL, const float* __restrict__ routB,
                          _Float16* __restrict__ w, float* __restrict__ b) {
  int tid = blockIdx.x * blockDim.x + threadIdx.x;  // 128*1024
  if (tid >= 128 * 1024) return;
  int n = tid >> 10, k = tid & 1023;
  float v = 0.f;
  if (n < 3) { if (k < 512) v = outL[n * 512 + k]; }
  else if (n < 96) { if (k >= 512) v = routL[(size_t)(n - 3) * 512 + (k - 512)]; }
  w[tid] = (_Float16)v;
  if (k == 0) b[n] = (n < 3) ? outB[n] : (n < 96 ? routB[n - 3] : 0.f);
}

// ---------------- f16 MFMA GEMM 128x128 (xg + heads) -----------------------
// CMODE 1: fp32 xg-swizzled: col' = (col&255)*4 + (col>>8)
// CMODE 3: heads: col<3 -> out[row*3+col]; 3<=col<96 -> rout[row*93+col-3]
template <bool GATHER, int CMODE>
__global__ __launch_bounds__(256) void mfma_gemm(
    const _Float16* __restrict__ A, int lda,
    const _Float16* __restrict__ W,
    const float* __restrict__ bias,
    const _Float16* __restrict__ vsrc, const int* __restrict__ fidx,
    void* __restrict__ C, int K) {
  __shared__ _Float16 Asm[128 * 64];  // 16 KB
  __shared__ _Float16 Bsm[128 * 64];  // 16 KB
  const int tid = threadIdx.x;
  const int w = tid >> 6, l = tid & 63;
  const int wr = w >> 1, wc = w & 1;
  const int m0 = blockIdx.y * 128, n0 = blockIdx.x * 128;
  const int lrow = l & 15, lk8 = (l >> 4) << 3;
  const int stg_r = l >> 3;
  const int stg_c = (l & 7) ^ stg_r;

  f4 acc[4][4] = {};

  for (int k0 = 0; k0 < K; k0 += 64) {
#pragma unroll
    for (int ii = 0; ii < 4; ++ii) {
      const int r = w * 32 + ii * 8 + stg_r;
      const _Float16* ga;
      if (GATHER) {
        const int token = m0 + r;
        const int slot = k0 >> 9;
        const int idx = fidx[token * 12 + slot];
        ga = vsrc + ((((size_t)(token >> 8) << 8) + idx) << 9) + (k0 & 511) + (stg_c << 3);
      } else {
        ga = A + (size_t)(m0 + r) * lda + k0 + (stg_c << 3);
      }
      stage16(ga, &Asm[(size_t)(w * 32 + ii * 8) * 64], l);
      const _Float16* gb = W + (size_t)(n0 + r) * K + k0 + (stg_c << 3);
      stage16(gb, &Bsm[(size_t)(w * 32 + ii * 8) * 64], l);
    }
    __syncthreads();
#pragma unroll
    for (int kk = 0; kk < 64; kk += 32) {
      const int c0 = (kk + lk8) >> 3;
      h8 af[4], bf[4];
#pragma unroll
      for (int m = 0; m < 4; ++m) {
        const int row = wr * 64 + m * 16 + lrow;
        af[m] = *(const h8*)&Asm[row * 64 + ((c0 ^ (row & 7)) << 3)];
      }
#pragma unroll
      for (int n = 0; n < 4; ++n) {
        const int row = wc * 64 + n * 16 + lrow;
        bf[n] = *(const h8*)&Bsm[row * 64 + ((c0 ^ (row & 7)) << 3)];
      }
#pragma unroll
      for (int m = 0; m < 4; ++m)
#pragma unroll
        for (int n = 0; n < 4; ++n)
          acc[m][n] = __builtin_amdgcn_mfma_f32_16x16x32_f16(af[m], bf[n], acc[m][n], 0, 0, 0);
    }
    __syncthreads();
  }
  // epilogue: C/D layout col=lane&15, row=(lane>>4)*4+reg (m89/m91)
#pragma unroll
  for (int n = 0; n < 4; ++n) {
    const int col = n0 + wc * 64 + n * 16 + lrow;
    const float bb = bias[col];
#pragma unroll
    for (int m = 0; m < 4; ++m) {
      const int rowb = m0 + wr * 64 + m * 16 + ((l >> 4) << 2);
#pragma unroll
      for (int r = 0; r < 4; ++r) {
        float v = acc[m][n][r] + bb;
        const size_t row = rowb + r;
        if (CMODE == 1) {
          ((float*)C)[row * kG4 + ((col & 255) * 4 + (col >> 8))] = v;
        } else if (CMODE == 2) {
          ((_Float16*)C)[row * kG4 + col] = (_Float16)tanhf(v);
        } else {
          if (col < 3)       ((float*)C)[row * 3 + col] = v;
          else if (col < 96) ((float*)C)[(size_t)kTok * 3 + row * 93 + (col - 3)] = v;
        }
      }
    }
  }
}

// ---------------- gather MFMA GEMM 256x128 (hid/rhid, K=6144) --------------
// 512 threads = 8 waves in 4(M)x2(N); per wave 64x64 out. LDS A 32K + B 16K.
__global__ __launch_bounds__(512) void mfma_gemm_g256(
    const _Float16* __restrict__ W,
    const float* __restrict__ bias,
    const _Float16* __restrict__ vsrc, const int* __restrict__ fidx,
    _Float16* __restrict__ C, int K) {
  __shared__ _Float16 Asm[256 * 64];  // 32 KB
  __shared__ _Float16 Bsm[128 * 64];  // 16 KB
  const int tid = threadIdx.x;
  const int w = tid >> 6, l = tid & 63;
  const int wr = w >> 1, wc = w & 1;            // 4 x 2 wave grid
  const int m0 = blockIdx.y * 256, n0 = blockIdx.x * 128;
  const int lrow = l & 15, lk8 = (l >> 4) << 3;
  const int stg_r = l >> 3;
  const int stg_c = (l & 7) ^ stg_r;

  f4 acc[4][4] = {};

  for (int k0 = 0; k0 < K; k0 += 64) {
#pragma unroll
    for (int ii = 0; ii < 4; ++ii) {
      const int token = m0 + w * 32 + ii * 8 + stg_r;
      const int slot = k0 >> 9;
      const int idx = fidx[token * 12 + slot];
      const _Float16* ga =
          vsrc + ((((size_t)(token >> 8) << 8) + idx) << 9) + (k0 & 511) + (stg_c << 3);
      stage16(ga, &Asm[(size_t)(w * 32 + ii * 8) * 64], l);
    }
#pragma unroll
    for (int ii = 0; ii < 2; ++ii) {
      const int r = w * 16 + ii * 8 + stg_r;
      const _Float16* gb = W + (size_t)(n0 + r) * K + k0 + (stg_c << 3);
      stage16(gb, &Bsm[(size_t)(w * 16 + ii * 8) * 64], l);
    }
    __syncthreads();
#pragma unroll
    for (int kk = 0; kk < 64; kk += 32) {
      const int c0 = (kk + lk8) >> 3;
      h8 af[4], bf[4];
#pragma unroll
      for (int m = 0; m < 4; ++m) {
        const int row = wr * 64 + m * 16 + lrow;
        af[m] = *(const h8*)&Asm[row * 64 + ((c0 ^ (row & 7)) << 3)];
      }
#pragma unroll
      for (int n = 0; n < 4; ++n) {
        const int row = wc * 64 + n * 16 + lrow;
        bf[n] = *(const h8*)&Bsm[row * 64 + ((c0 ^ (row & 7)) << 3)];
      }
#pragma unroll
      for (int m = 0; m < 4; ++m)
#pragma unroll
        for (int n = 0; n < 4; ++n)
          acc[m][n] = __builtin_amdgcn_mfma_f32_16x16x32_f16(af[m], bf[n], acc[m][n], 0, 0, 0);
    }
    __syncthreads();
  }
#pragma unroll
  for (int n = 0; n < 4; ++n) {
    const int col = n0 + wc * 64 + n * 16 + lrow;
    const float bb = bias[col];
#pragma unroll
    for (int m = 0; m < 4; ++m) {
      const int rowb = m0 + wr * 64 + m * 16 + ((l >> 4) << 2);
#pragma unroll
      for (int r = 0; r < 4; ++r) {
        float v = acc[m][n][r] + bb;
        C[(size_t)(rowb + r) * kG4 + col] = (_Float16)tanhf(v);
      }
    }
  }
}

// ---------------- LSTM recurrence v8: spill-free AND launchable ------------
// grid 128: dir = bid&1, row = bid>>1. 512 threads: pair (t, t^1) owns
// column c = t>>1 over k-half kh = t&1. amdgpu_waves_per_eu(2) pins the
// VGPR cap at 512/2 = 256 (launch_bounds' 2nd arg lowers as min-blocks/CU:
// =2 gave a 128 cap + scratch spill; =1 allowed >256 -> unlaunchable).
// Weights per gate: 48 pairs VGPR (192 regs, ~230 peak) + 16 pairs in
// swizzled LDS (128 KB). Per step: 16 h b128 + 16 weight b128 reads, 256
// fdot2, DPP pair-combine, exp-based nonlin, single barrier.
__global__ __attribute__((amdgpu_flat_work_group_size(512, 512), amdgpu_waves_per_eu(2)))
void lstm_rec_kernel(
    const float* __restrict__ xg_f, const float* __restrict__ xg_b,
    const float* __restrict__ Whh_f, const float* __restrict__ Whh_b,
    _Float16* __restrict__ out /* [B][S][512] fp16 */) {
  __shared__ uint4 wlds4[16 * 512];                    // 128 KB weight slice
  __shared__ __align__(16) _Float16 hbuf[2][kH];       // double-buffered h

  const int bid = blockIdx.x;
  const int dir = bid & 1;
  const int row = bid >> 1;
  const float* xg  = dir ? xg_b : xg_f;
  const float* Whh = dir ? Whh_b : Whh_f;
  const int t = threadIdx.x;
  const int c  = t >> 1;     // column 0..255
  const int kh = t & 1;      // k-half
  const int kbase = kh * 128;
  const int tsw = t ^ ((t >> 3) & 7);   // bank-spread swizzle

  // ---- one-time: weights for 4 gates of column c, k in [kbase,kbase+128) --
  h2 wv[4][48];
#pragma unroll
  for (int g = 0; g < 4; ++g) {
    const float2* wr = (const float2*)(Whh + (size_t)(g * kH + c) * kH + kbase);
#pragma unroll
    for (int p = 0; p < 48; ++p) {
      float2 f = wr[p];
      h2 a; a.x = (_Float16)f.x; a.y = (_Float16)f.y;
      wv[g][p] = a;
    }
#pragma unroll
    for (int q = 0; q < 4; ++q) {         // pairs 48..63 -> LDS
      unsigned u[4];
#pragma unroll
      for (int i = 0; i < 4; ++i) {
        float2 f = wr[48 + 4 * q + i];
        h2 a; a.x = (_Float16)f.x; a.y = (_Float16)f.y;
        u[i] = __builtin_bit_cast(unsigned, a);
      }
      wlds4[(g * 4 + q) * 512 + tsw] = make_uint4(u[0], u[1], u[2], u[3]);
    }
  }
  if (t < kH) hbuf[1][t] = (_Float16)0.f;   // step 0 reads hbuf[1]
  float c_state = 0.f;
  __syncthreads();

  const float* xgr = xg + (size_t)(row * kS) * kG4;
  const int sstep = dir ? -1 : 1;
  int s = dir ? (kS - 1) : 0;

  for (int it = 0; it < kS; ++it) {
    // current step's xg (independent of h; latency hides under the dot)
    const float4 xv = *(const float4*)(xgr + (size_t)s * kG4 + 4 * c);

    float a0 = 0.f, a1 = 0.f, a2 = 0.f, a3 = 0.f;
    const uint4* hh = ((const uint4*)hbuf[(it & 1) ^ 1]) + kh * 16;
    // VGPR-resident weight pairs (p = 0..47), h uint4 0..11
#pragma unroll
    for (int u = 0; u < 12; ++u) {
      uint4 hv = hh[u];
      h2 h0 = __builtin_bit_cast(h2, hv.x);
      h2 h1 = __builtin_bit_cast(h2, hv.y);
      h2 hx = __builtin_bit_cast(h2, hv.z);
      h2 h3 = __builtin_bit_cast(h2, hv.w);
      a0 = dot2acc(wv[0][4*u+0], h0, a0); a0 = dot2acc(wv[0][4*u+1], h1, a0);
      a0 = dot2acc(wv[0][4*u+2], hx, a0); a0 = dot2acc(wv[0][4*u+3], h3, a0);
      a1 = dot2acc(wv[1][4*u+0], h0, a1); a1 = dot2acc(wv[1][4*u+1], h1, a1);
      a1 = dot2acc(wv[1][4*u+2], hx, a1); a1 = dot2acc(wv[1][4*u+3], h3, a1);
      a2 = dot2acc(wv[2][4*u+0], h0, a2); a2 = dot2acc(wv[2][4*u+1], h1, a2);
      a2 = dot2acc(wv[2][4*u+2], hx, a2); a2 = dot2acc(wv[2][4*u+3], h3, a2);
      a3 = dot2acc(wv[3][4*u+0], h0, a3); a3 = dot2acc(wv[3][4*u+1], h1, a3);
      a3 = dot2acc(wv[3][4*u+2], hx, a3); a3 = dot2acc(wv[3][4*u+3], h3, a3);
    }
    // LDS-resident weight pairs (p = 48..63), h uint4 12..15
#pragma unroll
    for (int q = 0; q < 4; ++q) {
      uint4 hv = hh[12 + q];
      h2 h0 = __builtin_bit_cast(h2, hv.x);
      h2 h1 = __builtin_bit_cast(h2, hv.y);
      h2 hx = __builtin_bit_cast(h2, hv.z);
      h2 h3 = __builtin_bit_cast(h2, hv.w);
      uint4 w0 = wlds4[(0 * 4 + q) * 512 + tsw];
      uint4 w1 = wlds4[(1 * 4 + q) * 512 + tsw];
      uint4 w2 = wlds4[(2 * 4 + q) * 512 + tsw];
      uint4 w3 = wlds4[(3 * 4 + q) * 512 + tsw];
      a0 = dot2acc(__builtin_bit_cast(h2, w0.x), h0, a0);
      a0 = dot2acc(__builtin_bit_cast(h2, w0.y), h1, a0);
      a0 = dot2acc(__builtin_bit_cast(h2, w0.z), hx, a0);
      a0 = dot2acc(__builtin_bit_cast(h2, w0.w), h3, a0);
      a1 = dot2acc(__builtin_bit_cast(h2, w1.x), h0, a1);
      a1 = dot2acc(__builtin_bit_cast(h2, w1.y), h1, a1);
      a1 = dot2acc(__builtin_bit_cast(h2, w1.z), hx, a1);
      a1 = dot2acc(__builtin_bit_cast(h2, w1.w), h3, a1);
      a2 = dot2acc(__builtin_bit_cast(h2, w2.x), h0, a2);
      a2 = dot2acc(__builtin_bit_cast(h2, w2.y), h1, a2);
      a2 = dot2acc(__builtin_bit_cast(h2, w2.z), hx, a2);
      a2 = dot2acc(__builtin_bit_cast(h2, w2.w), h3, a2);
      a3 = dot2acc(__builtin_bit_cast(h2, w3.x), h0, a3);
      a3 = dot2acc(__builtin_bit_cast(h2, w3.y), h1, a3);
      a3 = dot2acc(__builtin_bit_cast(h2, w3.z), hx, a3);
      a3 = dot2acc(__builtin_bit_cast(h2, w3.w), h3, a3);
    }
    // combine k-halves (DPP, VALU pipe); xg added once (same value both lanes)
    float s0 = dppadd1(a0) + xv.x;
    float s1 = dppadd1(a1) + xv.y;
    float s2 = dppadd1(a2) + xv.z;
    float s3 = dppadd1(a3) + xv.w;
    // nonlinearity (redundant in both lanes; keeps c_state without exchange)
    float i_ = sigf(s0);
    float f_ = sigf(s1);
    float g_ = tanhfast(s2);
    float o_ = sigf(s3);
    c_state = f_ * c_state + i_ * g_;
    float h = o_ * tanhfast(c_state);
    if (!kh) {
      hbuf[it & 1][c] = (_Float16)h;
      out[((size_t)(row * kS + s)) * kLD + dir * kH + c] = (_Float16)h;
    }
    s += sstep;
    __syncthreads();
  }
}

// ---------------------------------------------------------------------------
extern "C" void kernel_launch(void* const* d_in, const int* in_sizes, int n_in,
                              void* d_out, int out_size, void* d_ws, size_t ws_size,
                              hipStream_t stream) {
  const int*   word_ids = (const int*)d_in[0];
  const int*   pos_ids  = (const int*)d_in[1];
  const int*   feat_idx = (const int*)d_in[2];
  const float* wlookup  = (const float*)d_in[3];
  const float* plookup  = (const float*)d_in[4];
  const float* Wih1f = (const float*)d_in[5];
  const float* Whh1f = (const float*)d_in[6];
  const float* bih1f = (const float*)d_in[7];
  const float* bhh1f = (const float*)d_in[8];
  const float* Wih1b = (const float*)d_in[9];
  const float* Whh1b = (const float*)d_in[10];
  const float* bih1b = (const float*)d_in[11];
  const float* bhh1b = (const float*)d_in[12];
  const float* Wih2f = (const float*)d_in[13];
  const float* Whh2f = (const float*)d_in[14];
  const float* bih2f = (const float*)d_in[15];
  const float* bhh2f = (const float*)d_in[16];
  const float* Wih2b = (const float*)d_in[17];
  const float* Whh2b = (const float*)d_in[18];
  const float* bih2b = (const float*)d_in[19];
  const float* bhh2b = (const float*)d_in[20];
  const float* hidLayer  = (const float*)d_in[21];
  const float* hidBias   = (const float*)d_in[22];
  const float* outLayer  = (const float*)d_in[23];
  const float* outBias   = (const float*)d_in[24];
  const float* rhidLayer = (const float*)d_in[25];
  const float* rhidBias  = (const float*)d_in[26];
  const float* routLayer = (const float*)d_in[27];
  const float* routBias  = (const float*)d_in[28];

  float* ws = (float*)d_ws;
  // workspace layout (float units; fp16 buffers counted as half-floats)
  const size_t F_IVECH = 0;
  const size_t F_XGF   = F_IVECH + (size_t)kTok * 192 / 2;
  const size_t F_XGB   = F_XGF + (size_t)kTok * kG4;         // fp32 (swizzled)
  const size_t F_V1H   = F_XGB + (size_t)kTok * kG4;
  const size_t F_V2H   = F_V1H + (size_t)kTok * kLD / 2;
  const size_t F_WHA   = F_V2H + (size_t)kTok * kLD / 2;
  const size_t F_WHB   = F_WHA + (size_t)2 * kG4 * 192 / 2;
  const size_t F_WHID  = F_WHB + (size_t)2 * kG4 * 512 / 2;
  const size_t F_BSUM  = F_WHID + (size_t)kG4 * 6144 / 2;
  const size_t F_HB    = F_BSUM + 4 * kG4;
  const size_t F_W96   = F_HB + kG4;
  const size_t F_B96   = F_W96 + (size_t)128 * kG4 / 2;
  const size_t F_END   = F_B96 + 128;
  const size_t F_HID   = F_XGF;                              // overlay after rec L2
  if (ws_size < F_END * sizeof(float)) return;

  _Float16* ivec_h = (_Float16*)(ws + F_IVECH);
  float*    xgs_f  = ws + F_XGF;
  float*    xgs_b  = ws + F_XGB;
  _Float16* vec1h  = (_Float16*)(ws + F_V1H);
  _Float16* vec2h  = (_Float16*)(ws + F_V2H);
  _Float16* whA    = (_Float16*)(ws + F_WHA);
  _Float16* whB    = (_Float16*)(ws + F_WHB);
  _Float16* whid   = (_Float16*)(ws + F_WHID);
  float*    bsum   = ws + F_BSUM;
  float*    hb     = ws + F_HB;
  _Float16* w96    = (_Float16*)(ws + F_W96);
  float*    b96    = ws + F_B96;
  _Float16* hidc_h = (_Float16*)(ws + F_HID);
  float*    outp   = (float*)d_out;

  // 1. weight/bias prep + embeddings
  prep_bias<<<16, 256, 0, stream>>>(bih1f, bhh1f, bih1b, bhh1b,
                                    bih2f, bhh2f, bih2b, bhh2b, bsum);
  concat_bias<<<4, 256, 0, stream>>>(hidBias, rhidBias, hb);
  build_w96<<<512, 256, 0, stream>>>(outLayer, outBias, routLayer, routBias, w96, b96);
  f2h_pad<<<(1024 * 48 + 255) / 256, 256, 0, stream>>>(Wih1f, whA, 1024, 160, 192);
  f2h_pad<<<(1024 * 48 + 255) / 256, 256, 0, stream>>>(Wih1b, whA + 1024 * 192, 1024, 160, 192);
  f2h_pad<<<(1024 * 128 + 255) / 256, 256, 0, stream>>>(Wih2f, whB, 1024, 512, 512);
  f2h_pad<<<(1024 * 128 + 255) / 256, 256, 0, stream>>>(Wih2b, whB + 1024 * 512, 1024, 512, 512);
  f2h_pad<<<(512 * 1536 + 255) / 256, 256, 0, stream>>>(hidLayer, whid, 512, 6144, 6144);
  f2h_pad<<<(512 * 1536 + 255) / 256, 256, 0, stream>>>(rhidLayer, whid + (size_t)512 * 6144,
                                                        512, 6144, 6144);
  embed_h<<<(kTok * 24 + 255) / 256, 256, 0, stream>>>(word_ids, pos_ids,
                                                       wlookup, plookup, ivec_h);
  // 2. layer-1 input gates (K=192, zero-padded), xg-swizzled output
  mfma_gemm<false, 1><<<dim3(8, 128), 256, 0, stream>>>(
      ivec_h, 192, whA, bsum + 0, nullptr, nullptr, xgs_f, 192);
  mfma_gemm<false, 1><<<dim3(8, 128), 256, 0, stream>>>(
      ivec_h, 192, whA + 1024 * 192, bsum + 1024, nullptr, nullptr, xgs_b, 192);
  // 3. layer-1 recurrence -> fp16
  lstm_rec_kernel<<<128, 512, 0, stream>>>(xgs_f, xgs_b, Whh1f, Whh1b, vec1h);
  // 4. layer-2 input gates (K=512), xg-swizzled output
  mfma_gemm<false, 1><<<dim3(8, 128), 256, 0, stream>>>(
      vec1h, 512, whB, bsum + 2048, nullptr, nullptr, xgs_f, 512);
  mfma_gemm<false, 1><<<dim3(8, 128), 256, 0, stream>>>(
      vec1h, 512, whB + 1024 * 512, bsum + 3072, nullptr, nullptr, xgs_b, 512);
  // 5. layer-2 recurrence -> fp16
  lstm_rec_kernel<<<128, 512, 0, stream>>>(xgs_f, xgs_b, Whh2f, Whh2b, vec2h);
  // 6. gather + hid/rhid MFMA GEMM, 256x128 tile (K=6144) -> fp16 hidc
  mfma_gemm_g256<<<dim3(8, 64), 512, 0, stream>>>(
      whid, hb, vec2h, feat_idx, hidc_h, 6144);
  // 7. heads: one MFMA GEMM, K=1024, N-tile 128 (cols 0-2 out, 3-95 rout)
  mfma_gemm<false, 3><<<dim3(1, 128), 256, 0, stream>>>(
      hidc_h, kG4, w96, b96, nullptr, nullptr, outp, kG4);
}